// Round 4
// baseline (158.253 us; speedup 1.0000x reference)
//
#include <hip/hip_runtime.h>

// Problem constants
#define B_SZ   8
#define T_SEQ  2048
#define C_DIM  1024
#define H_DIM  128

typedef _Float16 half8   __attribute__((ext_vector_type(8)));
typedef _Float16 half4_t __attribute__((ext_vector_type(4)));
typedef float    f32x4   __attribute__((ext_vector_type(4)));

#define MFMA(a, b, c) __builtin_amdgcn_mfma_f32_16x16x32_f16(a, b, c, 0, 0, 0)

// ---------------------------------------------------------------------------
// prep: W [C][H] fp32 -> WT [H][C] half (3 weights).  grid (512,3) x 256
// ---------------------------------------------------------------------------
__global__ __launch_bounds__(256) void prep_kernel(
    const float* __restrict__ Wk, const float* __restrict__ Wq,
    const float* __restrict__ Wv, _Float16* __restrict__ WT_all)
{
    const int w = blockIdx.y;
    const float* W = (w == 0) ? Wk : (w == 1) ? Wq : Wv;
    _Float16* dst = WT_all + (size_t)w * (C_DIM * H_DIM);
    int tid = blockIdx.x * 256 + threadIdx.x;
    int c = tid >> 7;
    int h = tid & (H_DIM - 1);
    dst[(size_t)h * C_DIM + c] = (_Float16)W[tid];
}

// ---------------------------------------------------------------------------
// proj: out[m][n] = sum_k x[m][k]*W[k][n], M=16384 K=1024 N=128.
// R0 structure (4 waves, 32x64/wave, 12 waves/CU) + R12 CHANGE (T2):
// LDS tiles use power-of-2 row stride (64 halfs = 128 B) with a 16B-slot
// XOR swizzle  slot ^= (row & 7)  on BOTH write and read.  The old +8-half
// pads rotated banks by 4 dwords/row, but ds_read_b128 fragment reads
// (16 rows x fixed 16B col) still collapsed onto ~8 bank-groups = ~8-way
// conflict = ~2.9x LDS-pipe slowdown (m136/m214-r268: pads do NOT fix
// this pattern; XOR does, +89% on the attn host kernel).
// ---------------------------------------------------------------------------
__global__ __launch_bounds__(256, 3) void proj_kernel(
    const float* __restrict__ x, const _Float16* __restrict__ WT_all,
    _Float16* __restrict__ q, _Float16* __restrict__ k, _Float16* __restrict__ vT)
{
    __shared__ _Float16 xs [64][64];     //  8 KiB, 8 slots/row
    __shared__ _Float16 wsh[128][64];    // 16 KiB, 8 slots/row

    const int w  = blockIdx.y;
    const int m0 = blockIdx.x * 64;
    const _Float16* WT = WT_all + (size_t)w * (C_DIM * H_DIM);

    const int t    = threadIdx.x;
    const int wave = t >> 6, lane = t & 63;
    const int quad = lane >> 4, l15 = lane & 15;
    const int wm = (wave >> 1) * 32;
    const int wn = (wave & 1) * 64;

    f32x4 acc[2][4] = {};

    const int srow_ = t >> 3;            // 0..31
    const int sslot = t & 7;             // 16B slot 0..7

    for (int k0 = 0; k0 < C_DIM; k0 += 64) {
        __syncthreads();
        // x: 64x64 fp32 -> fp16, 2 half8 per thread
        #pragma unroll
        for (int p = 0; p < 2; ++p) {
            int row = p * 32 + srow_;
            const float* xsrc = x + (size_t)(m0 + row) * C_DIM + k0 + sslot * 8;
            float4 a = ((const float4*)xsrc)[0];
            float4 b = ((const float4*)xsrc)[1];
            half8 hv = { (_Float16)a.x, (_Float16)a.y, (_Float16)a.z, (_Float16)a.w,
                         (_Float16)b.x, (_Float16)b.y, (_Float16)b.z, (_Float16)b.w };
            *(half8*)(&xs[row][(sslot ^ (row & 7)) * 8]) = hv;
        }
        // W: 128x64 fp16, 4 half8 per thread
        #pragma unroll
        for (int p = 0; p < 4; ++p) {
            int row = p * 32 + srow_;
            *(half8*)(&wsh[row][(sslot ^ (row & 7)) * 8]) =
                *(const half8*)(WT + (size_t)row * C_DIM + k0 + sslot * 8);
        }
        __syncthreads();
        #pragma unroll
        for (int kb = 0; kb < 2; ++kb) {
            half8 af[2], bf[4];
            #pragma unroll
            for (int i = 0; i < 2; ++i) {
                int row = wm + i * 16 + l15;
                af[i] = *(const half8*)(&xs[row][((kb * 4 + quad) ^ (row & 7)) * 8]);
            }
            #pragma unroll
            for (int j = 0; j < 4; ++j) {
                int row = wn + j * 16 + l15;
                bf[j] = *(const half8*)(&wsh[row][((kb * 4 + quad) ^ (row & 7)) * 8]);
            }
            #pragma unroll
            for (int i = 0; i < 2; ++i)
                #pragma unroll
                for (int j = 0; j < 4; ++j)
                    acc[i][j] = MFMA(af[i], bf[j], acc[i][j]);
        }
    }

    if (w != 2) {
        _Float16* outN = (w == 0) ? k : q;
        #pragma unroll
        for (int i = 0; i < 2; ++i) {
            int row = m0 + wm + i * 16 + quad * 4;
            #pragma unroll
            for (int j = 0; j < 4; ++j) {
                int col = wn + j * 16 + l15;
                #pragma unroll
                for (int r = 0; r < 4; ++r)
                    outN[(size_t)(row + r) * H_DIM + col] = (_Float16)acc[i][j][r];
            }
        }
    } else {
        #pragma unroll
        for (int i = 0; i < 2; ++i) {
            int grow = m0 + wm + i * 16 + quad * 4;
            int bb = grow >> 11, tp = grow & (T_SEQ - 1);
            #pragma unroll
            for (int j = 0; j < 4; ++j) {
                int h = wn + j * 16 + l15;
                half4_t hv = { (_Float16)acc[i][j][0], (_Float16)acc[i][j][1],
                               (_Float16)acc[i][j][2], (_Float16)acc[i][j][3] };
                *(half4_t*)(vT + ((size_t)bb * H_DIM + h) * T_SEQ + tp) = hv;
            }
        }
    }
}

// ---------------------------------------------------------------------------
// attn: 4 waves/block, qtile 64, kv tile 64, kv-chunk 512.  R0 structure +
// R12 CHANGE (T2): ks/vts/ps moved to power-of-2 strides with the same
// 16B-slot XOR swizzle on write and read (K fragments, V fragments, and the
// P round-trip were all ~8-way bank-conflicted with the old pads).
// ---------------------------------------------------------------------------
__global__ __launch_bounds__(256, 3) void attn_kernel(
    const _Float16* __restrict__ q, const _Float16* __restrict__ k,
    const _Float16* __restrict__ vT,
    _Float16* __restrict__ pO, float* __restrict__ ml, float* __restrict__ out)
{
    __shared__ _Float16 ks [64][128];    // 16 KiB, 16 slots/row
    __shared__ _Float16 vts[128][64];    // 16 KiB,  8 slots/row
    __shared__ _Float16 ps [4][16][64];  //  8 KiB,  8 slots/row   (total 40 KiB)

    const int n = blockIdx.x;
    const int b = n & 7;
    const int u = n >> 3;                // 0..79, heavy-first

    int qt = 31, c = 0;
    {
        int acc = 0;
        #pragma unroll 1
        while (true) {
            int nch = (qt >> 3) + 1;
            if (u < acc + nch) { c = u - acc; break; }
            acc += nch; --qt;
        }
    }
    const bool partial = (qt >= 8);

    const int kt0 = c * 8;
    const int kt1 = min(qt, c * 8 + 7);

    const int t = threadIdx.x;
    const int wave = t >> 6, lane = t & 63;
    const int quad = lane >> 4, l15 = lane & 15;
    const int qrow0 = qt * 64 + wave * 16;

    const _Float16* qb = q  + (size_t)b * T_SEQ * H_DIM;
    const _Float16* kp = k  + (size_t)b * T_SEQ * H_DIM;
    const _Float16* vp = vT + (size_t)b * H_DIM * T_SEQ;

    half8 aq[4];
    #pragma unroll
    for (int i = 0; i < 4; ++i) {
        half8 v = *(const half8*)(qb + (size_t)(qrow0 + l15) * H_DIM + i * 32 + quad * 8);
        #pragma unroll
        for (int j = 0; j < 8; ++j) v[j] = v[j] * (_Float16)0.088388347648318447f;
        aq[i] = v;
    }

    f32x4 accO[8] = {};
    float lrun[4] = {0.0f, 0.0f, 0.0f, 0.0f};

    const int krow = t >> 4, kseg = t & 15;   // K: 16 rows x 16 slots
    const int vrow = t >> 3, vseg = t & 7;    // V: 32 rows x  8 slots

    for (int kt = kt0; kt <= kt1; ++kt) {
        const int kv0 = kt * 64;
        __syncthreads();
        #pragma unroll
        for (int p = 0; p < 4; ++p) {
            int row = p * 16 + krow;
            *(half8*)(&ks[row][(kseg ^ (row & 7)) * 8]) =
                *(const half8*)(kp + (size_t)(kv0 + row) * H_DIM + kseg * 8);
        }
        #pragma unroll
        for (int p = 0; p < 4; ++p) {
            int h = p * 32 + vrow;
            *(half8*)(&vts[h][(vseg ^ (h & 7)) * 8]) =
                *(const half8*)(vp + (size_t)h * T_SEQ + kv0 + vseg * 8);
        }
        __syncthreads();

        f32x4 sacc[4] = {};
        #pragma unroll
        for (int kbi = 0; kbi < 4; ++kbi) {
            #pragma unroll
            for (int nt = 0; nt < 4; ++nt) {
                int row = nt * 16 + l15;
                half8 bf = *(const half8*)(&ks[row][((kbi * 4 + quad) ^ (row & 7)) * 8]);
                sacc[nt] = MFMA(aq[kbi], bf, sacc[nt]);
            }
        }

        if (kv0 + 63 > qrow0) {
            #pragma unroll
            for (int nt = 0; nt < 4; ++nt) {
                int key = kv0 + nt * 16 + l15;
                #pragma unroll
                for (int r = 0; r < 4; ++r) {
                    int qr = qrow0 + quad * 4 + r;
                    if (key > qr) sacc[nt][r] = -1.0e30f;
                }
            }
        }

        #pragma unroll
        for (int nt = 0; nt < 4; ++nt)
            #pragma unroll
            for (int r = 0; r < 4; ++r) {
                float p = __expf(sacc[nt][r]);
                lrun[r] += p;
                int prow = quad * 4 + r;
                int col  = nt * 16 + l15;
                int slot = (col >> 3) ^ (prow & 7);
                ps[wave][prow][slot * 8 + (col & 7)] = (_Float16)p;
            }

        half8 pf0 = *(const half8*)(&ps[wave][l15][(quad ^ (l15 & 7)) * 8]);
        half8 pf1 = *(const half8*)(&ps[wave][l15][((4 + quad) ^ (l15 & 7)) * 8]);
        #pragma unroll
        for (int nt = 0; nt < 8; ++nt) {
            int row = nt * 16 + l15;
            half8 vf0 = *(const half8*)(&vts[row][(quad ^ (row & 7)) * 8]);
            half8 vf1 = *(const half8*)(&vts[row][((4 + quad) ^ (row & 7)) * 8]);
            accO[nt] = MFMA(pf0, vf0, accO[nt]);
            accO[nt] = MFMA(pf1, vf1, accO[nt]);
        }
    }

    #pragma unroll
    for (int r = 0; r < 4; ++r) {
        lrun[r] += __shfl_xor(lrun[r], 1);
        lrun[r] += __shfl_xor(lrun[r], 2);
        lrun[r] += __shfl_xor(lrun[r], 4);
        lrun[r] += __shfl_xor(lrun[r], 8);
    }

    if (partial) {
        const int pid = b * 72 + u;
        const int urow = wave * 16 + quad * 4;
        #pragma unroll
        for (int nt = 0; nt < 8; ++nt)
            #pragma unroll
            for (int r = 0; r < 4; ++r)
                pO[(size_t)pid * 8192 + (urow + r) * 128 + nt * 16 + l15]
                    = (_Float16)accO[nt][r];
        if (l15 == 0) {
            #pragma unroll
            for (int r = 0; r < 4; ++r)
                ml[(size_t)pid * 64 + urow + r] = lrun[r];
        }
    } else {
        float invl[4];
        #pragma unroll
        for (int r = 0; r < 4; ++r) invl[r] = 1.0f / lrun[r];
        #pragma unroll
        for (int nt = 0; nt < 8; ++nt)
            #pragma unroll
            for (int r = 0; r < 4; ++r)
                out[((size_t)b * T_SEQ + qrow0 + quad * 4 + r) * H_DIM + nt * 16 + l15]
                    = accO[nt][r] * invl[r];
    }
}

// ---------------------------------------------------------------------------
// combine: out = (sum_c pO[c]) / (sum_c l[c]); nc = qt/8+1 in 2..4. (unchanged)
// ---------------------------------------------------------------------------
__global__ __launch_bounds__(256) void attn_combine(
    const _Float16* __restrict__ pO, const float* __restrict__ ml,
    float* __restrict__ out)
{
    const int n  = blockIdx.x;
    const int b  = n & 7;
    const int m  = n >> 3;               // 0..95
    const int rg = m & 3;
    const int qt = 8 + (m >> 2);         // 8..31
    const int nc = (qt >> 3) + 1;        // 2..4

    int u0 = 0;
    #pragma unroll 1
    for (int q2 = 31; q2 > qt; --q2) u0 += (q2 >> 3) + 1;
    const size_t pid0 = (size_t)b * 72 + u0;

    const int t   = threadIdx.x;
    const int row = rg * 16 + (t >> 4);
    const int h   = (t & 15) * 8;

    float lsum = 0.0f;
    #pragma unroll 1
    for (int c = 0; c < nc; ++c)
        lsum += ml[(pid0 + c) * 64 + row];

    float acc[8] = {};
    #pragma unroll 1
    for (int c = 0; c < nc; ++c) {
        half8 po = *(const half8*)(pO + (pid0 + c) * 8192 + row * 128 + h);
        #pragma unroll
        for (int j = 0; j < 8; ++j) acc[j] += (float)po[j];
    }

    const float inv = 1.0f / lsum;
    float* op = out + ((size_t)b * T_SEQ + qt * 64 + row) * H_DIM + h;
    f32x4 o0 = { acc[0] * inv, acc[1] * inv, acc[2] * inv, acc[3] * inv };
    f32x4 o1 = { acc[4] * inv, acc[5] * inv, acc[6] * inv, acc[7] * inv };
    *(f32x4*)(op)     = o0;
    *(f32x4*)(op + 4) = o1;
}

// ---------------------------------------------------------------------------
extern "C" void kernel_launch(void* const* d_in, const int* in_sizes, int n_in,
                              void* d_out, int out_size, void* d_ws, size_t ws_size,
                              hipStream_t stream)
{
    const float* x  = (const float*)d_in[0];
    const float* Wk = (const float*)d_in[1];
    const float* Wq = (const float*)d_in[2];
    const float* Wv = (const float*)d_in[3];
    float* out = (float*)d_out;

    _Float16* ws = (_Float16*)d_ws;
    const size_t NQKV = (size_t)B_SZ * T_SEQ * H_DIM;          // 2,097,152
    _Float16* q_ws  = ws;
    _Float16* k_ws  = ws + NQKV;
    _Float16* vT_ws = ws + 2 * NQKV;
    _Float16* wt_ws = ws + 3 * NQKV;                           // 3*C*H halfs
    _Float16* pO_ws = wt_ws + 3 * (size_t)(C_DIM * H_DIM);     // 576 units * 8192 halfs
    float*    ml_ws = (float*)(pO_ws + (size_t)576 * 8192);    // 576 * 64 floats

    prep_kernel <<<dim3(512, 3), 256, 0, stream>>>(Wk, Wq, Wv, wt_ws);
    proj_kernel <<<dim3(256, 3), 256, 0, stream>>>(x, wt_ws, q_ws, k_ws, vT_ws);
    attn_kernel <<<640, 256, 0, stream>>>(q_ws, k_ws, vT_ws, pO_ws, ml_ws, out);
    attn_combine<<<768, 256, 0, stream>>>(pO_ws, ml_ws, out);
}

// Round 5
// 153.522 us; speedup vs baseline: 1.0308x; 1.0308x over previous
//
#include <hip/hip_runtime.h>

// Problem constants
#define B_SZ   8
#define T_SEQ  2048
#define C_DIM  1024
#define H_DIM  128

typedef _Float16 half8   __attribute__((ext_vector_type(8)));
typedef _Float16 half4_t __attribute__((ext_vector_type(4)));
typedef float    f32x4   __attribute__((ext_vector_type(4)));

#define MFMA(a, b, c) __builtin_amdgcn_mfma_f32_16x16x32_f16(a, b, c, 0, 0, 0)

// ---------------------------------------------------------------------------
// prep: W [C][H] fp32 -> WT [H][C] half (3 weights), coalesced both sides
// via a 64x64 LDS transpose tile.  (Old version wrote 2B at 2KB stride =
// 64 cache lines per wave.)  grid (32,3) x 256.
// ---------------------------------------------------------------------------
__global__ __launch_bounds__(256) void prep_kernel(
    const float* __restrict__ Wk, const float* __restrict__ Wq,
    const float* __restrict__ Wv, _Float16* __restrict__ WT_all)
{
    __shared__ _Float16 tile[64][68];    // [h][c] 64x64 +pad

    const int w = blockIdx.y;
    const float* W = (w == 0) ? Wk : (w == 1) ? Wq : Wv;
    _Float16* dst = WT_all + (size_t)w * (C_DIM * H_DIM);

    const int bx = blockIdx.x;           // 0..31
    const int c0 = (bx >> 1) * 64;       // 16 c-tiles
    const int h0 = (bx & 1) * 64;        // 2 h-tiles
    const int t  = threadIdx.x;

    // read: coalesced along h (float4), scatter-transpose into LDS
    {
        const int hl = (t & 15) * 4;     // 0..60
        const int cl = t >> 4;           // 0..15
        #pragma unroll
        for (int p = 0; p < 4; ++p) {
            int c = cl + p * 16;
            float4 f = *(const float4*)(W + (size_t)(c0 + c) * H_DIM + h0 + hl);
            tile[hl + 0][c] = (_Float16)f.x;
            tile[hl + 1][c] = (_Float16)f.y;
            tile[hl + 2][c] = (_Float16)f.z;
            tile[hl + 3][c] = (_Float16)f.w;
        }
    }
    __syncthreads();
    // write: coalesced along c (half4)
    {
        const int hr = t >> 4;           // 0..15
        const int cc = (t & 15) * 4;
        #pragma unroll
        for (int p = 0; p < 4; ++p) {
            int h = hr + p * 16;
            half4_t v = { tile[h][cc], tile[h][cc + 1], tile[h][cc + 2], tile[h][cc + 3] };
            *(half4_t*)(dst + (size_t)(h0 + h) * C_DIM + c0 + cc) = v;
        }
    }
}

// ---------------------------------------------------------------------------
// proj: out[m][n] = sum_k x[m][k]*W[k][n], M=16384 K=1024 N=128, 3 weights.
// R13 REDESIGN — read x ONCE.  Evidence: R3's counters showed proj at
// 41.2 us with FETCH only 12.6 MB but a 201 MB x demand (3 reads of 67 MB,
// once per blockIdx.y) served by L3 at 201MB/41.2us = 4.9 TB/s -> proj is
// L3-BW bound.  (Explains why prefetch/occupancy/ratio/swizzle were all
// null: none reduced bytes.)  Each block now owns a 32-row x stripe and
// computes ALL THREE projections from one staged x tile: x L3 traffic
// 201 -> 67 MB.  Grid 512 = 2 blocks/CU (8 waves/CU); LDS 58.5 KB -> 2
// resident.  Per K-step/wave: 16 ds_read_b128 -> 24 MFMA.
// w==0 -> k [B*T][H], w==1 -> q, w==2 -> vT [B][H][T] (transposed).
// ---------------------------------------------------------------------------
__global__ __launch_bounds__(256, 2) void proj_kernel(
    const float* __restrict__ x, const _Float16* __restrict__ WT_all,
    _Float16* __restrict__ q, _Float16* __restrict__ k, _Float16* __restrict__ vT)
{
    __shared__ _Float16 xs [32][72];        //  4.5 KiB
    __shared__ _Float16 wsh[3][128][72];    // 54 KiB

    const int m0 = blockIdx.x * 32;

    const int t    = threadIdx.x;
    const int wave = t >> 6, lane = t & 63;
    const int quad = lane >> 4, l15 = lane & 15;
    const int wc = wave * 32;               // wave's 32-col slice (of 128)

    f32x4 acc[3][2][2] = {};

    const int srow = t >> 3;                // 0..31
    const int scol = (t & 7) * 8;           // half8 slot

    for (int k0 = 0; k0 < C_DIM; k0 += 64) {
        __syncthreads();
        // x: 32x64 fp32 -> fp16, one half8 per thread
        {
            const float* xsrc = x + (size_t)(m0 + srow) * C_DIM + k0 + scol;
            float4 a = ((const float4*)xsrc)[0];
            float4 b = ((const float4*)xsrc)[1];
            half8 hv = { (_Float16)a.x, (_Float16)a.y, (_Float16)a.z, (_Float16)a.w,
                         (_Float16)b.x, (_Float16)b.y, (_Float16)b.z, (_Float16)b.w };
            *(half8*)(&xs[srow][scol]) = hv;
        }
        // W: 3 x 128x64 fp16, 12 half8 per thread (L2-resident source)
        #pragma unroll
        for (int w = 0; w < 3; ++w) {
            const _Float16* WT = WT_all + (size_t)w * (C_DIM * H_DIM);
            #pragma unroll
            for (int p = 0; p < 4; ++p) {
                int row = p * 32 + srow;
                *(half8*)(&wsh[w][row][scol]) =
                    *(const half8*)(WT + (size_t)row * C_DIM + k0 + scol);
            }
        }
        __syncthreads();
        #pragma unroll
        for (int kb = 0; kb < 2; ++kb) {
            half8 af[2];
            #pragma unroll
            for (int i = 0; i < 2; ++i)
                af[i] = *(const half8*)(&xs[i * 16 + l15][kb * 32 + quad * 8]);
            #pragma unroll
            for (int w = 0; w < 3; ++w) {
                half8 bf[2];
                #pragma unroll
                for (int j = 0; j < 2; ++j)
                    bf[j] = *(const half8*)(&wsh[w][wc + j * 16 + l15][kb * 32 + quad * 8]);
                #pragma unroll
                for (int i = 0; i < 2; ++i)
                    #pragma unroll
                    for (int j = 0; j < 2; ++j)
                        acc[w][i][j] = MFMA(af[i], bf[j], acc[w][i][j]);
            }
        }
    }

    // epilogue: k, q direct; v transposed
    #pragma unroll
    for (int w = 0; w < 2; ++w) {
        _Float16* outN = (w == 0) ? k : q;
        #pragma unroll
        for (int i = 0; i < 2; ++i) {
            int row = m0 + i * 16 + quad * 4;
            #pragma unroll
            for (int j = 0; j < 2; ++j) {
                int col = wc + j * 16 + l15;
                #pragma unroll
                for (int r = 0; r < 4; ++r)
                    outN[(size_t)(row + r) * H_DIM + col] = (_Float16)acc[w][i][j][r];
            }
        }
    }
    #pragma unroll
    for (int i = 0; i < 2; ++i) {
        int grow = m0 + i * 16 + quad * 4;
        int bb = grow >> 11, tp = grow & (T_SEQ - 1);
        #pragma unroll
        for (int j = 0; j < 2; ++j) {
            int h = wc + j * 16 + l15;
            half4_t hv = { (_Float16)acc[2][i][j][0], (_Float16)acc[2][i][j][1],
                           (_Float16)acc[2][i][j][2], (_Float16)acc[2][i][j][3] };
            *(half4_t*)(vT + ((size_t)bb * H_DIM + h) * T_SEQ + tp) = hv;
        }
    }
}

// ---------------------------------------------------------------------------
// attn: 4 waves/block, qtile 64, kv tile 64, kv-chunk 512.  EXACT R0 version
// (proven ~30 us) — single-variable attribution of the proj change.
// ---------------------------------------------------------------------------
__global__ __launch_bounds__(256, 3) void attn_kernel(
    const _Float16* __restrict__ q, const _Float16* __restrict__ k,
    const _Float16* __restrict__ vT,
    _Float16* __restrict__ pO, float* __restrict__ ml, float* __restrict__ out)
{
    __shared__ _Float16 ks [64][136];    // 17408 B
    __shared__ _Float16 vts[128][72];    // 18432 B
    __shared__ _Float16 ps [4][16][72];  //  9216 B   (total 45056)

    const int n = blockIdx.x;
    const int b = n & 7;
    const int u = n >> 3;                // 0..79, heavy-first

    int qt = 31, c = 0;
    {
        int acc = 0;
        #pragma unroll 1
        while (true) {
            int nch = (qt >> 3) + 1;
            if (u < acc + nch) { c = u - acc; break; }
            acc += nch; --qt;
        }
    }
    const bool partial = (qt >= 8);

    const int kt0 = c * 8;
    const int kt1 = min(qt, c * 8 + 7);

    const int t = threadIdx.x;
    const int wave = t >> 6, lane = t & 63;
    const int quad = lane >> 4, l15 = lane & 15;
    const int qrow0 = qt * 64 + wave * 16;

    const _Float16* qb = q  + (size_t)b * T_SEQ * H_DIM;
    const _Float16* kp = k  + (size_t)b * T_SEQ * H_DIM;
    const _Float16* vp = vT + (size_t)b * H_DIM * T_SEQ;

    half8 aq[4];
    #pragma unroll
    for (int i = 0; i < 4; ++i) {
        half8 v = *(const half8*)(qb + (size_t)(qrow0 + l15) * H_DIM + i * 32 + quad * 8);
        #pragma unroll
        for (int j = 0; j < 8; ++j) v[j] = v[j] * (_Float16)0.088388347648318447f;
        aq[i] = v;
    }

    f32x4 accO[8] = {};
    float lrun[4] = {0.0f, 0.0f, 0.0f, 0.0f};

    const int krow = t >> 4, kseg = t & 15;
    const int vrow = t >> 3, vseg = t & 7;

    for (int kt = kt0; kt <= kt1; ++kt) {
        const int kv0 = kt * 64;
        __syncthreads();
        #pragma unroll
        for (int p = 0; p < 4; ++p) {
            int row = p * 16 + krow;
            *(half8*)(&ks[row][kseg * 8]) =
                *(const half8*)(kp + (size_t)(kv0 + row) * H_DIM + kseg * 8);
        }
        #pragma unroll
        for (int p = 0; p < 4; ++p) {
            int h = p * 32 + vrow;
            *(half8*)(&vts[h][vseg * 8]) =
                *(const half8*)(vp + (size_t)h * T_SEQ + kv0 + vseg * 8);
        }
        __syncthreads();

        f32x4 sacc[4] = {};
        #pragma unroll
        for (int kbi = 0; kbi < 4; ++kbi) {
            #pragma unroll
            for (int nt = 0; nt < 4; ++nt) {
                half8 bf = *(const half8*)(&ks[nt * 16 + l15][kbi * 32 + quad * 8]);
                sacc[nt] = MFMA(aq[kbi], bf, sacc[nt]);
            }
        }

        if (kv0 + 63 > qrow0) {
            #pragma unroll
            for (int nt = 0; nt < 4; ++nt) {
                int key = kv0 + nt * 16 + l15;
                #pragma unroll
                for (int r = 0; r < 4; ++r) {
                    int qr = qrow0 + quad * 4 + r;
                    if (key > qr) sacc[nt][r] = -1.0e30f;
                }
            }
        }

        #pragma unroll
        for (int nt = 0; nt < 4; ++nt)
            #pragma unroll
            for (int r = 0; r < 4; ++r) {
                float p = __expf(sacc[nt][r]);
                lrun[r] += p;
                ps[wave][quad * 4 + r][nt * 16 + l15] = (_Float16)p;
            }

        half8 pf0 = *(const half8*)(&ps[wave][l15][quad * 8]);
        half8 pf1 = *(const half8*)(&ps[wave][l15][32 + quad * 8]);
        #pragma unroll
        for (int nt = 0; nt < 8; ++nt) {
            half8 vf0 = *(const half8*)(&vts[nt * 16 + l15][quad * 8]);
            half8 vf1 = *(const half8*)(&vts[nt * 16 + l15][32 + quad * 8]);
            accO[nt] = MFMA(pf0, vf0, accO[nt]);
            accO[nt] = MFMA(pf1, vf1, accO[nt]);
        }
    }

    #pragma unroll
    for (int r = 0; r < 4; ++r) {
        lrun[r] += __shfl_xor(lrun[r], 1);
        lrun[r] += __shfl_xor(lrun[r], 2);
        lrun[r] += __shfl_xor(lrun[r], 4);
        lrun[r] += __shfl_xor(lrun[r], 8);
    }

    if (partial) {
        const int pid = b * 72 + u;
        const int urow = wave * 16 + quad * 4;
        #pragma unroll
        for (int nt = 0; nt < 8; ++nt)
            #pragma unroll
            for (int r = 0; r < 4; ++r)
                pO[(size_t)pid * 8192 + (urow + r) * 128 + nt * 16 + l15]
                    = (_Float16)accO[nt][r];
        if (l15 == 0) {
            #pragma unroll
            for (int r = 0; r < 4; ++r)
                ml[(size_t)pid * 64 + urow + r] = lrun[r];
        }
    } else {
        float invl[4];
        #pragma unroll
        for (int r = 0; r < 4; ++r) invl[r] = 1.0f / lrun[r];
        #pragma unroll
        for (int nt = 0; nt < 8; ++nt)
            #pragma unroll
            for (int r = 0; r < 4; ++r)
                out[((size_t)b * T_SEQ + qrow0 + quad * 4 + r) * H_DIM + nt * 16 + l15]
                    = accO[nt][r] * invl[r];
    }
}

// ---------------------------------------------------------------------------
// combine: out = (sum_c pO[c]) / (sum_c l[c]); nc = qt/8+1 in 2..4. (unchanged)
// ---------------------------------------------------------------------------
__global__ __launch_bounds__(256) void attn_combine(
    const _Float16* __restrict__ pO, const float* __restrict__ ml,
    float* __restrict__ out)
{
    const int n  = blockIdx.x;
    const int b  = n & 7;
    const int m  = n >> 3;               // 0..95
    const int rg = m & 3;
    const int qt = 8 + (m >> 2);         // 8..31
    const int nc = (qt >> 3) + 1;        // 2..4

    int u0 = 0;
    #pragma unroll 1
    for (int q2 = 31; q2 > qt; --q2) u0 += (q2 >> 3) + 1;
    const size_t pid0 = (size_t)b * 72 + u0;

    const int t   = threadIdx.x;
    const int row = rg * 16 + (t >> 4);
    const int h   = (t & 15) * 8;

    float lsum = 0.0f;
    #pragma unroll 1
    for (int c = 0; c < nc; ++c)
        lsum += ml[(pid0 + c) * 64 + row];

    float acc[8] = {};
    #pragma unroll 1
    for (int c = 0; c < nc; ++c) {
        half8 po = *(const half8*)(pO + (pid0 + c) * 8192 + row * 128 + h);
        #pragma unroll
        for (int j = 0; j < 8; ++j) acc[j] += (float)po[j];
    }

    const float inv = 1.0f / lsum;
    float* op = out + ((size_t)b * T_SEQ + qt * 64 + row) * H_DIM + h;
    f32x4 o0 = { acc[0] * inv, acc[1] * inv, acc[2] * inv, acc[3] * inv };
    f32x4 o1 = { acc[4] * inv, acc[5] * inv, acc[6] * inv, acc[7] * inv };
    *(f32x4*)(op)     = o0;
    *(f32x4*)(op + 4) = o1;
}

// ---------------------------------------------------------------------------
extern "C" void kernel_launch(void* const* d_in, const int* in_sizes, int n_in,
                              void* d_out, int out_size, void* d_ws, size_t ws_size,
                              hipStream_t stream)
{
    const float* x  = (const float*)d_in[0];
    const float* Wk = (const float*)d_in[1];
    const float* Wq = (const float*)d_in[2];
    const float* Wv = (const float*)d_in[3];
    float* out = (float*)d_out;

    _Float16* ws = (_Float16*)d_ws;
    const size_t NQKV = (size_t)B_SZ * T_SEQ * H_DIM;          // 2,097,152
    _Float16* q_ws  = ws;
    _Float16* k_ws  = ws + NQKV;
    _Float16* vT_ws = ws + 2 * NQKV;
    _Float16* wt_ws = ws + 3 * NQKV;                           // 3*C*H halfs
    _Float16* pO_ws = wt_ws + 3 * (size_t)(C_DIM * H_DIM);     // 576 units * 8192 halfs
    float*    ml_ws = (float*)(pO_ws + (size_t)576 * 8192);    // 576 * 64 floats

    prep_kernel <<<dim3(32, 3), 256, 0, stream>>>(Wk, Wq, Wv, wt_ws);
    proj_kernel <<<512, 256, 0, stream>>>(x, wt_ws, q_ws, k_ws, vT_ws);
    attn_kernel <<<640, 256, 0, stream>>>(q_ws, k_ws, vT_ws, pO_ws, ml_ws, out);
    attn_combine<<<768, 256, 0, stream>>>(pO_ws, ml_ws, out);
}